// Round 13
// baseline (111.122 us; speedup 1.0000x reference)
//
#include <hip/hip_runtime.h>
#include <math.h>
#include <float.h>

// CDistLoss on MI355X — round 11 design (third submission; two infra timeouts).
// Slice-private histograms (no global atomics), odd LDS hist stride
// (bank spread), k_gram fused into k_count's grid.
// out[i] = (1/4095) * sum_el sqrt(d2_el) * (cd/S_d + 0.1)/(ca/S_a + 0.1)
// p = prefix of 256-bin histogram at bin(d2_el) (incl self; bit-identical d2
// in gram/count paths), ca = r+1, cd = (p-1)-(r+1);
// S_a = sum(4097-p), S_d = 4095*4096/2 - S_a; sample_weight == 1.

#define N 4096
#define DF 128
#define NCLS 64
#define MAXP 128
#define DSTR 128          // d2f col stride (floats)
#define NB 256            // histogram bins
#define ROWS 16           // rows per count block
#define CS 4              // col splits (slice-private hist copies)
#define HPAD 257          // odd LDS hist stride: bank = (row+bin)%32
#define HROW (CS * NB)    // 1024 u32 per sample row in global hist
#define BSCALE 0.5f       // bin = clamp(int(d2*0.5), 0, 255)
#define KCNT ((N / ROWS) * CS)   // 1024 count blocks

typedef __bf16 bf16x8 __attribute__((ext_vector_type(8)));
typedef float f32x4 __attribute__((ext_vector_type(4)));
typedef unsigned int u32x4 __attribute__((ext_vector_type(4)));

static __device__ __forceinline__ unsigned short f2bf(float f) {
  unsigned int u = __float_as_uint(f);
  unsigned int r = (u + 0x7fffu + ((u >> 16) & 1u)) >> 16;  // RNE
  return (unsigned short)r;
}
static __device__ __forceinline__ int d2bin(float d2) {
  int b = (int)(d2 * BSCALE);
  return min(max(b, 0), NB - 1);
}

// ---- kernel 1: blocks 0..1023: fp32->bf16 + row norms; block 1024: classes ----
__global__ void k_prep(const float* __restrict__ x, const int* __restrict__ y,
                       unsigned short* __restrict__ xb, float* __restrict__ sq,
                       unsigned int* __restrict__ cls_cnt, int* __restrict__ cls_idx,
                       int* __restrict__ pos) {
  __shared__ unsigned int c_cnt[NCLS];
  const int tid = threadIdx.x;
  if (blockIdx.x < 1024) {
    const int wave = tid >> 6, lane = tid & 63;
    const int row = (blockIdx.x << 2) + wave;
    const float2 v = *(const float2*)&x[row * DF + (lane << 1)];
    unsigned int b = (unsigned int)f2bf(v.x) | ((unsigned int)f2bf(v.y) << 16);
    *(unsigned int*)&xb[row * DF + (lane << 1)] = b;
    float s = v.x * v.x + v.y * v.y;
    #pragma unroll
    for (int off = 32; off; off >>= 1) s += __shfl_down(s, off);
    if (lane == 0) sq[row] = s;
  } else {
    if (tid < NCLS) c_cnt[tid] = 0u;
    __syncthreads();
    for (int k = tid; k < N; k += 256) {
      const int c = y[k];
      unsigned int p = atomicAdd(&c_cnt[c], 1u);
      if (p >= MAXP) p = MAXP - 1;   // statistically unreachable
      cls_idx[c * MAXP + p] = k;
      pos[k] = (int)p;
    }
    __syncthreads();
    if (tid < NCLS) cls_cnt[tid] = min(c_cnt[tid], (unsigned int)MAXP);
  }
}

// ---- kernel 2 (fused): blocks < KCNT: Gram tiles + slice-private histogram;
//                        blocks >= KCNT: per-class Gram -> d2f ----
__global__ __launch_bounds__(256, 4) void k_cg(
    const unsigned short* __restrict__ xb, const float* __restrict__ sq,
    const unsigned int* __restrict__ cls_cnt, const int* __restrict__ cls_idx,
    unsigned int* __restrict__ hist4, float* __restrict__ d2f) {
  __shared__ unsigned int histL[ROWS][HPAD];  // 16.4 KB
  __shared__ float sqcL[1024];                // 4 KB
  __shared__ int plist[MAXP];                 // 0.5 KB
  __shared__ float sqL[MAXP];                 // 0.5 KB
  const int tid = threadIdx.x;
  const int wave = tid >> 6, lane = tid & 63;
  const int l15 = lane & 15, lg = lane >> 4;

  if (blockIdx.x < KCNT) {
    // ---------------- count path: 16 rows x 1024 cols ----------------
    const int rb = blockIdx.x >> 2;
    const int cs = blockIdx.x & 3;
    const int row0 = rb * ROWS;
    const int col0 = cs * 1024;

    for (int e = tid; e < ROWS * HPAD; e += 256) ((unsigned int*)histL)[e] = 0u;
    for (int e = tid; e < 1024; e += 256) sqcL[e] = sq[col0 + e];

    const u32x4* ap = (const u32x4*)(xb + (size_t)(row0 + l15) * DF + (lg << 3));
    const bf16x8 a0 = __builtin_bit_cast(bf16x8, ap[0]);
    const bf16x8 a1 = __builtin_bit_cast(bf16x8, ap[4]);
    const bf16x8 a2 = __builtin_bit_cast(bf16x8, ap[8]);
    const bf16x8 a3 = __builtin_bit_cast(bf16x8, ap[12]);
    float sqa[4];
    #pragma unroll
    for (int r = 0; r < 4; ++r) sqa[r] = sq[row0 + lg * 4 + r];
    __syncthreads();

    const int jbase = wave * 256;        // each wave: 256 cols = 16 tiles
    #pragma unroll
    for (int t = 0; t < 16; ++t) {
      const int jc = jbase + t * 16;
      const u32x4* bp = (const u32x4*)(xb + (size_t)(col0 + jc + l15) * DF + (lg << 3));
      const bf16x8 b0 = __builtin_bit_cast(bf16x8, bp[0]);
      const bf16x8 b1 = __builtin_bit_cast(bf16x8, bp[4]);
      const bf16x8 b2 = __builtin_bit_cast(bf16x8, bp[8]);
      const bf16x8 b3 = __builtin_bit_cast(bf16x8, bp[12]);
      f32x4 acc = {0.f, 0.f, 0.f, 0.f};
      acc = __builtin_amdgcn_mfma_f32_16x16x32_bf16(a0, b0, acc, 0, 0, 0);
      acc = __builtin_amdgcn_mfma_f32_16x16x32_bf16(a1, b1, acc, 0, 0, 0);
      acc = __builtin_amdgcn_mfma_f32_16x16x32_bf16(a2, b2, acc, 0, 0, 0);
      acc = __builtin_amdgcn_mfma_f32_16x16x32_bf16(a3, b3, acc, 0, 0, 0);
      const float sqc = sqcL[jc + l15];
      #pragma unroll
      for (int r = 0; r < 4; ++r) {
        const int lr = lg * 4 + r;
        atomicAdd(&histL[lr][d2bin(fmaf(-2.0f, acc[r], sqa[r] + sqc))], 1u);
      }
    }
    __syncthreads();
    // plain coalesced slice store — no global atomics, no pre-zeroed hist
    for (int e = tid; e < ROWS * NB; e += 256)
      hist4[(size_t)(row0 + (e >> 8)) * HROW + cs * NB + (e & 255)] = histL[e >> 8][e & 255];
  } else {
    // ---------------- gram path: per-class d2f ----------------
    const int gb = blockIdx.x - KCNT;
    const int c = gb >> 3;               // class
    const int ti = gb & 7;               // tile-row
    const int M = (int)cls_cnt[c];
    const int nT = (M + 15) >> 4;
    if (ti >= nT) return;                // uniform per block
    for (int m = tid; m < M; m += 256) {
      const int j = cls_idx[c * MAXP + m];
      plist[m] = j;
      sqL[m] = sq[j];
    }
    __syncthreads();
    const int ra = min(ti * 16 + l15, M - 1);
    const u32x4* ap = (const u32x4*)(xb + (size_t)plist[ra] * DF + (lg << 3));
    const bf16x8 a0 = __builtin_bit_cast(bf16x8, ap[0]);
    const bf16x8 a1 = __builtin_bit_cast(bf16x8, ap[4]);
    const bf16x8 a2 = __builtin_bit_cast(bf16x8, ap[8]);
    const bf16x8 a3 = __builtin_bit_cast(bf16x8, ap[12]);
    float sqa[4];
    #pragma unroll
    for (int r = 0; r < 4; ++r) sqa[r] = sqL[min(ti * 16 + lg * 4 + r, M - 1)];
    float* drow = d2f + (size_t)c * (MAXP * DSTR);
    for (int tj = wave; tj < nT; tj += 4) {
      const int rb2 = min(tj * 16 + l15, M - 1);
      const u32x4* bp = (const u32x4*)(xb + (size_t)plist[rb2] * DF + (lg << 3));
      const bf16x8 b0 = __builtin_bit_cast(bf16x8, bp[0]);
      const bf16x8 b1 = __builtin_bit_cast(bf16x8, bp[4]);
      const bf16x8 b2 = __builtin_bit_cast(bf16x8, bp[8]);
      const bf16x8 b3 = __builtin_bit_cast(bf16x8, bp[12]);
      f32x4 acc = {0.f, 0.f, 0.f, 0.f};
      acc = __builtin_amdgcn_mfma_f32_16x16x32_bf16(a0, b0, acc, 0, 0, 0);
      acc = __builtin_amdgcn_mfma_f32_16x16x32_bf16(a1, b1, acc, 0, 0, 0);
      acc = __builtin_amdgcn_mfma_f32_16x16x32_bf16(a2, b2, acc, 0, 0, 0);
      acc = __builtin_amdgcn_mfma_f32_16x16x32_bf16(a3, b3, acc, 0, 0, 0);
      const float sqc = sqL[rb2];
      #pragma unroll
      for (int r = 0; r < 4; ++r) {
        const int row = ti * 16 + lg * 4 + r;
        drow[row * DSTR + tj * 16 + l15] = fmaf(-2.0f, acc[r], sqa[r] + sqc);
      }
    }
  }
}

// ---- kernel 3: fused rank + 4-slice prefix + score (one wave per sample) ----
__global__ void k_final(const int* __restrict__ y, const int* __restrict__ pos,
                        const unsigned int* __restrict__ cls_cnt,
                        const float* __restrict__ d2f,
                        const unsigned int* __restrict__ hist4,
                        float* __restrict__ out) {
  __shared__ float rowL[MAXP];
  __shared__ unsigned int preL[NB];
  const int i = blockIdx.x;
  const int lane = threadIdx.x;  // 64 threads
  const int c = y[i];
  const int rw = pos[i];
  const int M = (int)cls_cnt[c];
  const float* drow = d2f + (size_t)c * (MAXP * DSTR) + (size_t)rw * DSTR;
  rowL[lane] = drow[lane];
  rowL[lane + 64] = drow[lane + 64];
  // sum 4 slices, then 256-bin inclusive prefix via wave scan (4 bins/lane)
  const unsigned int* hrow = hist4 + (size_t)i * HROW;
  u32x4 h = *(const u32x4*)&hrow[lane << 2];
  #pragma unroll
  for (int s = 1; s < CS; ++s) {
    const u32x4 h2 = *(const u32x4*)&hrow[s * NB + (lane << 2)];
    h[0] += h2[0]; h[1] += h2[1]; h[2] += h2[2]; h[3] += h2[3];
  }
  const unsigned int s0 = h[0], s1 = s0 + h[1], s2 = s1 + h[2], s3 = s2 + h[3];
  unsigned int sc_ = s3;
  #pragma unroll
  for (int off = 1; off < 64; off <<= 1) {
    const unsigned int t = __shfl_up(sc_, off);
    if (lane >= off) sc_ += t;
  }
  const unsigned int base = sc_ - s3;
  preL[(lane << 2) + 0] = base + s0;
  preL[(lane << 2) + 1] = base + s1;
  preL[(lane << 2) + 2] = base + s2;
  preL[(lane << 2) + 3] = base + s3;
  __syncthreads();
  const float dself = rowL[rw];
  const int el0 = lane, el1 = lane + 64;
  const bool v0 = (el0 < M) && (el0 != rw);
  const bool v1 = (el1 < M) && (el1 != rw);
  const float dt0 = v0 ? rowL[el0] : 0.f;
  const float dt1 = v1 ? rowL[el1] : 0.f;
  int r0 = 0, r1 = 0;
  for (int s = 0; s < M; ++s) {
    const float ds = rowL[s];
    r0 += (ds < dt0 || (ds == dt0 && s < el0)) ? 1 : 0;
    r1 += (ds < dt1 || (ds == dt1 && s < el1)) ? 1 : 0;
  }
  r0 -= (dself < dt0 || (dself == dt0 && rw < el0)) ? 1 : 0;
  r1 -= (dself < dt1 || (dself == dt1 && rw < el1)) ? 1 : 0;
  const int pr0 = v0 ? (int)preL[d2bin(dt0)] : 0;
  const int pr1 = v1 ? (int)preL[d2bin(dt1)] : 0;
  int sa = 0;
  if (v0) sa += (N + 1) - pr0;
  if (v1) sa += (N + 1) - pr1;
  #pragma unroll
  for (int off = 32; off; off >>= 1) sa += __shfl_down(sa, off);
  sa = __shfl(sa, 0);
  const float Sa = (float)sa + 1e-7f;
  const float Sd = (float)(8386560 - sa) + 1e-7f;   // 4095*4096/2 - S_a
  float sc = 0.f;
  if (v0) {
    const float fa = (float)(r0 + 1) / Sa;
    const float fd = (float)((pr0 - 1) - (r0 + 1)) / Sd;
    sc += sqrtf(fmaxf(dt0, 1e-12f)) * (fd + 0.1f) / (fa + 0.1f);
  }
  if (v1) {
    const float fa = (float)(r1 + 1) / Sa;
    const float fd = (float)((pr1 - 1) - (r1 + 1)) / Sd;
    sc += sqrtf(fmaxf(dt1, 1e-12f)) * (fd + 0.1f) / (fa + 0.1f);
  }
  #pragma unroll
  for (int off = 32; off; off >>= 1) sc += __shfl_down(sc, off);
  if (lane == 0) out[i] = sc * (1.0f / 4095.0f);
}

extern "C" void kernel_launch(void* const* d_in, const int* in_sizes, int n_in,
                              void* d_out, int out_size, void* d_ws, size_t ws_size,
                              hipStream_t stream) {
  const float* x = (const float*)d_in[0];
  const int* y = (const int*)d_in[1];
  float* out = (float*)d_out;
  char* ws = (char*)d_ws;
  unsigned short* xb    = (unsigned short*)ws;                   // 1 MB @ 0
  float* sq             = (float*)(ws + 1048576);                // 16 KB
  unsigned int* cls_cnt = (unsigned int*)(ws + 1064960);         // 256 B
  int* cls_idx          = (int*)(ws + 1065216);                  // 32 KB
  int* pos              = (int*)(ws + 1097984);                  // 16 KB
  float* d2f            = (float*)(ws + 1114368);                // 4 MB
  unsigned int* hist4   = (unsigned int*)(ws + 5308672);         // 16 MB (4096 x 1024)

  k_prep<<<1025, 256, 0, stream>>>(x, y, xb, sq, cls_cnt, cls_idx, pos);
  k_cg<<<KCNT + NCLS * 8, 256, 0, stream>>>(xb, sq, cls_cnt, cls_idx, hist4, d2f);
  k_final<<<N, 64, 0, stream>>>(y, pos, cls_cnt, d2f, hist4, out);
}

// Round 14
// 99.135 us; speedup vs baseline: 1.1209x; 1.1209x over previous
//
#include <hip/hip_runtime.h>
#include <math.h>
#include <float.h>

// CDistLoss on MI355X — round 14: round-10 structure + 1-deep B prefetch.
// out[i] = (1/4095) * sum_el sqrt(d2_el) * (cd/S_d + 0.1)/(ca/S_a + 0.1)
// p = prefix of 256-bin histogram at bin(d2_el) (incl self; bit-identical d2
// in gram/count paths), ca = r+1, cd = (p-1)-(r+1);
// S_a = sum(4097-p), S_d = 4095*4096/2 - S_a; sample_weight == 1.
// R13 lesson: ROWS=16 + slice stores regressed (40.6us); count kernel is
// LATENCY-bound (Mfma 3%, VALU 26%, Occ 50%). Fix: prefetch next tile's
// B fragments before current tile's MFMA+epilogue.

#define N 4096
#define DF 128
#define NCLS 64
#define MAXP 128
#define DSTR 128          // d2f col stride (floats)
#define NB 256            // histogram bins
#define ROWS 32           // rows per count block
#define CS 8              // col splits -> 512 cols per block
#define HPAD 257          // odd LDS hist stride: bank = (row+bin)%32
#define BSCALE 0.5f       // bin = clamp(int(d2*0.5), 0, 255)
#define KCNT ((N / ROWS) * CS)   // 1024 count blocks

typedef __bf16 bf16x8 __attribute__((ext_vector_type(8)));
typedef float f32x4 __attribute__((ext_vector_type(4)));
typedef unsigned int u32x4 __attribute__((ext_vector_type(4)));

static __device__ __forceinline__ unsigned short f2bf(float f) {
  unsigned int u = __float_as_uint(f);
  unsigned int r = (u + 0x7fffu + ((u >> 16) & 1u)) >> 16;  // RNE
  return (unsigned short)r;
}
static __device__ __forceinline__ int d2bin(float d2) {
  int b = (int)(d2 * BSCALE);
  return min(max(b, 0), NB - 1);
}

// ---- kernel 1: blocks 0..1023: fp32->bf16 + row norms + zero hist slice;
//                block 1024: class bucketing ----
__global__ void k_prep(const float* __restrict__ x, const int* __restrict__ y,
                       unsigned short* __restrict__ xb, float* __restrict__ sq,
                       unsigned int* __restrict__ cls_cnt, int* __restrict__ cls_idx,
                       int* __restrict__ pos, unsigned int* __restrict__ hist) {
  __shared__ unsigned int c_cnt[NCLS];
  const int tid = threadIdx.x;
  if (blockIdx.x < 1024) {
    const int wave = tid >> 6, lane = tid & 63;
    const int row = (blockIdx.x << 2) + wave;
    const float2 v = *(const float2*)&x[row * DF + (lane << 1)];
    unsigned int b = (unsigned int)f2bf(v.x) | ((unsigned int)f2bf(v.y) << 16);
    *(unsigned int*)&xb[row * DF + (lane << 1)] = b;
    const u32x4 z = {0u, 0u, 0u, 0u};
    *(u32x4*)&hist[(size_t)blockIdx.x * 1024 + (tid << 2)] = z;  // 4 KB/block
    float s = v.x * v.x + v.y * v.y;
    #pragma unroll
    for (int off = 32; off; off >>= 1) s += __shfl_down(s, off);
    if (lane == 0) sq[row] = s;
  } else {
    if (tid < NCLS) c_cnt[tid] = 0u;
    __syncthreads();
    for (int k = tid; k < N; k += 256) {
      const int c = y[k];
      unsigned int p = atomicAdd(&c_cnt[c], 1u);
      if (p >= MAXP) p = MAXP - 1;   // statistically unreachable
      cls_idx[c * MAXP + p] = k;
      pos[k] = (int)p;
    }
    __syncthreads();
    if (tid < NCLS) cls_cnt[tid] = min(c_cnt[tid], (unsigned int)MAXP);
  }
}

// ---- kernel 2 (fused): blocks < KCNT: dual-acc Gram + histogram w/ prefetch;
//                        blocks >= KCNT: per-class Gram -> d2f ----
__global__ __launch_bounds__(256, 4) void k_cg(
    const unsigned short* __restrict__ xb, const float* __restrict__ sq,
    const unsigned int* __restrict__ cls_cnt, const int* __restrict__ cls_idx,
    unsigned int* __restrict__ hist, float* __restrict__ d2f) {
  __shared__ unsigned int histL[ROWS][HPAD];  // 32.9 KB
  __shared__ float sqcL[512];                 // 2 KB
  __shared__ int plist[MAXP];                 // 0.5 KB
  __shared__ float sqL[MAXP];                 // 0.5 KB
  const int tid = threadIdx.x;
  const int wave = tid >> 6, lane = tid & 63;
  const int l15 = lane & 15, lg = lane >> 4;

  if (blockIdx.x < KCNT) {
    // -------- count path: 32 rows x 512 cols, 8 tiles/wave, prefetched --------
    const int rb = blockIdx.x >> 3;
    const int cs = blockIdx.x & 7;
    const int row0 = rb * ROWS;
    const int col0 = cs * 512;

    for (int e = tid; e < ROWS * HPAD; e += 256) ((unsigned int*)histL)[e] = 0u;
    if (tid < 256) { sqcL[tid] = sq[col0 + tid]; sqcL[tid + 256] = sq[col0 + 256 + tid]; }

    const u32x4* apA = (const u32x4*)(xb + (size_t)(row0 + l15) * DF + (lg << 3));
    const u32x4* apB = (const u32x4*)(xb + (size_t)(row0 + 16 + l15) * DF + (lg << 3));
    const bf16x8 a0 = __builtin_bit_cast(bf16x8, apA[0]);
    const bf16x8 a1 = __builtin_bit_cast(bf16x8, apA[4]);
    const bf16x8 a2 = __builtin_bit_cast(bf16x8, apA[8]);
    const bf16x8 a3 = __builtin_bit_cast(bf16x8, apA[12]);
    const bf16x8 a4 = __builtin_bit_cast(bf16x8, apB[0]);
    const bf16x8 a5 = __builtin_bit_cast(bf16x8, apB[4]);
    const bf16x8 a6 = __builtin_bit_cast(bf16x8, apB[8]);
    const bf16x8 a7 = __builtin_bit_cast(bf16x8, apB[12]);
    float sqa0[4], sqa1[4];
    #pragma unroll
    for (int r = 0; r < 4; ++r) {
      sqa0[r] = sq[row0 + lg * 4 + r];
      sqa1[r] = sq[row0 + 16 + lg * 4 + r];
    }
    __syncthreads();

    const int jbase = wave * 128;        // 8 tiles of 16 cols per wave
    // prefetch tile 0
    const u32x4* bp0 = (const u32x4*)(xb + (size_t)(col0 + jbase + l15) * DF + (lg << 3));
    u32x4 f0 = bp0[0], f1 = bp0[4], f2 = bp0[8], f3 = bp0[12];
    #pragma unroll
    for (int t = 0; t < 8; ++t) {
      const int jc = jbase + t * 16;
      const bf16x8 b0 = __builtin_bit_cast(bf16x8, f0);
      const bf16x8 b1 = __builtin_bit_cast(bf16x8, f1);
      const bf16x8 b2 = __builtin_bit_cast(bf16x8, f2);
      const bf16x8 b3 = __builtin_bit_cast(bf16x8, f3);
      if (t < 7) {                       // issue next tile's loads NOW
        const u32x4* bp = (const u32x4*)(xb + (size_t)(col0 + jc + 16 + l15) * DF + (lg << 3));
        f0 = bp[0]; f1 = bp[4]; f2 = bp[8]; f3 = bp[12];
      }
      f32x4 acc0 = {0.f, 0.f, 0.f, 0.f};
      f32x4 acc1 = {0.f, 0.f, 0.f, 0.f};
      acc0 = __builtin_amdgcn_mfma_f32_16x16x32_bf16(a0, b0, acc0, 0, 0, 0);
      acc0 = __builtin_amdgcn_mfma_f32_16x16x32_bf16(a1, b1, acc0, 0, 0, 0);
      acc0 = __builtin_amdgcn_mfma_f32_16x16x32_bf16(a2, b2, acc0, 0, 0, 0);
      acc0 = __builtin_amdgcn_mfma_f32_16x16x32_bf16(a3, b3, acc0, 0, 0, 0);
      acc1 = __builtin_amdgcn_mfma_f32_16x16x32_bf16(a4, b0, acc1, 0, 0, 0);
      acc1 = __builtin_amdgcn_mfma_f32_16x16x32_bf16(a5, b1, acc1, 0, 0, 0);
      acc1 = __builtin_amdgcn_mfma_f32_16x16x32_bf16(a6, b2, acc1, 0, 0, 0);
      acc1 = __builtin_amdgcn_mfma_f32_16x16x32_bf16(a7, b3, acc1, 0, 0, 0);
      const float sqc = sqcL[jc + l15];
      #pragma unroll
      for (int r = 0; r < 4; ++r) {
        const int lr = lg * 4 + r;
        atomicAdd(&histL[lr][d2bin(fmaf(-2.0f, acc0[r], sqa0[r] + sqc))], 1u);
        atomicAdd(&histL[16 + lr][d2bin(fmaf(-2.0f, acc1[r], sqa1[r] + sqc))], 1u);
      }
    }
    __syncthreads();
    for (int e = tid; e < ROWS * NB; e += 256) {
      const unsigned int v = histL[e >> 8][e & 255];
      if (v) atomicAdd(&hist[(size_t)(row0 + (e >> 8)) * NB + (e & 255)], v);
    }
  } else {
    // ---------------- gram path: per-class d2f ----------------
    const int gb = blockIdx.x - KCNT;
    const int c = gb >> 3;               // class
    const int ti = gb & 7;               // tile-row
    const int M = (int)cls_cnt[c];
    const int nT = (M + 15) >> 4;
    if (ti >= nT) return;                // uniform per block
    for (int m = tid; m < M; m += 256) {
      const int j = cls_idx[c * MAXP + m];
      plist[m] = j;
      sqL[m] = sq[j];
    }
    __syncthreads();
    const int ra = min(ti * 16 + l15, M - 1);
    const u32x4* ap = (const u32x4*)(xb + (size_t)plist[ra] * DF + (lg << 3));
    const bf16x8 a0 = __builtin_bit_cast(bf16x8, ap[0]);
    const bf16x8 a1 = __builtin_bit_cast(bf16x8, ap[4]);
    const bf16x8 a2 = __builtin_bit_cast(bf16x8, ap[8]);
    const bf16x8 a3 = __builtin_bit_cast(bf16x8, ap[12]);
    float sqa[4];
    #pragma unroll
    for (int r = 0; r < 4; ++r) sqa[r] = sqL[min(ti * 16 + lg * 4 + r, M - 1)];
    float* drow = d2f + (size_t)c * (MAXP * DSTR);
    for (int tj = wave; tj < nT; tj += 4) {
      const int rb2 = min(tj * 16 + l15, M - 1);
      const u32x4* bp = (const u32x4*)(xb + (size_t)plist[rb2] * DF + (lg << 3));
      const bf16x8 b0 = __builtin_bit_cast(bf16x8, bp[0]);
      const bf16x8 b1 = __builtin_bit_cast(bf16x8, bp[4]);
      const bf16x8 b2 = __builtin_bit_cast(bf16x8, bp[8]);
      const bf16x8 b3 = __builtin_bit_cast(bf16x8, bp[12]);
      f32x4 acc = {0.f, 0.f, 0.f, 0.f};
      acc = __builtin_amdgcn_mfma_f32_16x16x32_bf16(a0, b0, acc, 0, 0, 0);
      acc = __builtin_amdgcn_mfma_f32_16x16x32_bf16(a1, b1, acc, 0, 0, 0);
      acc = __builtin_amdgcn_mfma_f32_16x16x32_bf16(a2, b2, acc, 0, 0, 0);
      acc = __builtin_amdgcn_mfma_f32_16x16x32_bf16(a3, b3, acc, 0, 0, 0);
      const float sqc = sqL[rb2];
      #pragma unroll
      for (int r = 0; r < 4; ++r) {
        const int row = ti * 16 + lg * 4 + r;
        drow[row * DSTR + tj * 16 + l15] = fmaf(-2.0f, acc[r], sqa[r] + sqc);
      }
    }
  }
}

// ---- kernel 3: fused rank + prefix + score (one wave per sample) ----
__global__ void k_final(const int* __restrict__ y, const int* __restrict__ pos,
                        const unsigned int* __restrict__ cls_cnt,
                        const float* __restrict__ d2f,
                        const unsigned int* __restrict__ hist,
                        float* __restrict__ out) {
  __shared__ float rowL[MAXP];
  __shared__ unsigned int preL[NB];
  const int i = blockIdx.x;
  const int lane = threadIdx.x;  // 64 threads
  const int c = y[i];
  const int rw = pos[i];
  const int M = (int)cls_cnt[c];
  const float* drow = d2f + (size_t)c * (MAXP * DSTR) + (size_t)rw * DSTR;
  rowL[lane] = drow[lane];
  rowL[lane + 64] = drow[lane + 64];
  // 256-bin inclusive prefix via wave scan (4 bins/lane)
  const u32x4 h = *(const u32x4*)&hist[(size_t)i * NB + (lane << 2)];
  const unsigned int s0 = h[0], s1 = s0 + h[1], s2 = s1 + h[2], s3 = s2 + h[3];
  unsigned int sc_ = s3;
  #pragma unroll
  for (int off = 1; off < 64; off <<= 1) {
    const unsigned int t = __shfl_up(sc_, off);
    if (lane >= off) sc_ += t;
  }
  const unsigned int base = sc_ - s3;
  preL[(lane << 2) + 0] = base + s0;
  preL[(lane << 2) + 1] = base + s1;
  preL[(lane << 2) + 2] = base + s2;
  preL[(lane << 2) + 3] = base + s3;
  __syncthreads();
  const float dself = rowL[rw];
  const int el0 = lane, el1 = lane + 64;
  const bool v0 = (el0 < M) && (el0 != rw);
  const bool v1 = (el1 < M) && (el1 != rw);
  const float dt0 = v0 ? rowL[el0] : 0.f;
  const float dt1 = v1 ? rowL[el1] : 0.f;
  int r0 = 0, r1 = 0;
  for (int s = 0; s < M; ++s) {
    const float ds = rowL[s];
    r0 += (ds < dt0 || (ds == dt0 && s < el0)) ? 1 : 0;
    r1 += (ds < dt1 || (ds == dt1 && s < el1)) ? 1 : 0;
  }
  r0 -= (dself < dt0 || (dself == dt0 && rw < el0)) ? 1 : 0;
  r1 -= (dself < dt1 || (dself == dt1 && rw < el1)) ? 1 : 0;
  const int pr0 = v0 ? (int)preL[d2bin(dt0)] : 0;
  const int pr1 = v1 ? (int)preL[d2bin(dt1)] : 0;
  int sa = 0;
  if (v0) sa += (N + 1) - pr0;
  if (v1) sa += (N + 1) - pr1;
  #pragma unroll
  for (int off = 32; off; off >>= 1) sa += __shfl_down(sa, off);
  sa = __shfl(sa, 0);
  const float Sa = (float)sa + 1e-7f;
  const float Sd = (float)(8386560 - sa) + 1e-7f;   // 4095*4096/2 - S_a
  float sc = 0.f;
  if (v0) {
    const float fa = (float)(r0 + 1) / Sa;
    const float fd = (float)((pr0 - 1) - (r0 + 1)) / Sd;
    sc += sqrtf(fmaxf(dt0, 1e-12f)) * (fd + 0.1f) / (fa + 0.1f);
  }
  if (v1) {
    const float fa = (float)(r1 + 1) / Sa;
    const float fd = (float)((pr1 - 1) - (r1 + 1)) / Sd;
    sc += sqrtf(fmaxf(dt1, 1e-12f)) * (fd + 0.1f) / (fa + 0.1f);
  }
  #pragma unroll
  for (int off = 32; off; off >>= 1) sc += __shfl_down(sc, off);
  if (lane == 0) out[i] = sc * (1.0f / 4095.0f);
}

extern "C" void kernel_launch(void* const* d_in, const int* in_sizes, int n_in,
                              void* d_out, int out_size, void* d_ws, size_t ws_size,
                              hipStream_t stream) {
  const float* x = (const float*)d_in[0];
  const int* y = (const int*)d_in[1];
  float* out = (float*)d_out;
  char* ws = (char*)d_ws;
  unsigned short* xb    = (unsigned short*)ws;                   // 1 MB @ 0
  float* sq             = (float*)(ws + 1048576);                // 16 KB
  unsigned int* cls_cnt = (unsigned int*)(ws + 1064960);         // 256 B
  int* cls_idx          = (int*)(ws + 1065216);                  // 32 KB
  int* pos              = (int*)(ws + 1097984);                  // 16 KB
  unsigned int* hist    = (unsigned int*)(ws + 1114368);         // 4 MB (4096 x 256)
  float* d2f            = (float*)(ws + 5308672);                // 4 MB -> 9.1 MB total

  k_prep<<<1025, 256, 0, stream>>>(x, y, xb, sq, cls_cnt, cls_idx, pos, hist);
  k_cg<<<KCNT + NCLS * 8, 256, 0, stream>>>(xb, sq, cls_cnt, cls_idx, hist, d2f);
  k_final<<<N, 64, 0, stream>>>(y, pos, cls_cnt, d2f, hist, out);
}